// Round 14
// baseline (276.273 us; speedup 1.0000x reference)
//
#include <hip/hip_runtime.h>
#include <math.h>

// Volume geometry (1,1,96,128,128)
#define DIMD 96
#define DIMH 128
#define DIMW 128
#define N_ELEM (DIMD*DIMH*DIMW)   // 1,572,864
#define N4 (N_ELEM/4)

#define RBLOCKS 512
// z-chunk depth 24: 4 chunks, steps/output 33/24 = 1.375 (vs 21/12 = 1.75)

__device__ __forceinline__ float sigmoidf_(float x) { return 1.0f / (1.0f + expf(-x)); }
__device__ __forceinline__ float4 mk4(float a, float b, float c, float d) {
    float4 r; r.x = a; r.y = b; r.z = c; r.w = d; return r;
}
__device__ __forceinline__ float4 ldf4(const float* p) { return *(const float4*)p; }

// Barrier WITHOUT vmcnt drain: LDS producer->consumer fence only.
__device__ __forceinline__ void pipe_barrier() {
    asm volatile("s_waitcnt lgkmcnt(0)" ::: "memory");
    __builtin_amdgcn_s_barrier();
    asm volatile("" ::: "memory");
}

template<bool MX> __device__ __forceinline__ float op2(float a, float b) {
    return MX ? fmaxf(a, b) : fminf(a, b);
}
template<bool MX> __device__ __forceinline__ float op3(float a, float b, float c) {
    return op2<MX>(op2<MX>(a, b), c);   // -> v_min3/v_max3
}
template<bool MX> __device__ __forceinline__ float4 vop(float4 a, float4 b) {
    return mk4(op2<MX>(a.x,b.x), op2<MX>(a.y,b.y), op2<MX>(a.z,b.z), op2<MX>(a.w,b.w));
}
// window starts at +0 / +1 / +2 within concat(A,B)
template<bool MX> __device__ __forceinline__ float4 shift3(float4 A, float4 B) {
    return mk4(op3<MX>(A.x,A.y,A.z), op3<MX>(A.y,A.z,A.w),
               op3<MX>(A.z,A.w,B.x), op3<MX>(A.w,B.x,B.y));
}
template<bool MX> __device__ __forceinline__ float4 shift3b(float4 A, float4 B) {
    return mk4(op3<MX>(A.y,A.z,A.w), op3<MX>(A.z,A.w,B.x),
               op3<MX>(A.w,B.x,B.y), op3<MX>(B.x,B.y,B.z));
}
template<bool MX> __device__ __forceinline__ float4 shift3c(float4 A, float4 B) {
    return mk4(op3<MX>(A.z,A.w,B.x), op3<MX>(A.w,B.x,B.y),
               op3<MX>(B.x,B.y,B.z), op3<MX>(B.y,B.z,B.w));
}
template<bool MX> __device__ __forceinline__ float4 xy3(const float* base, int stride, int y, int xq) {
    float4 acc;
    #pragma unroll
    for (int dy = 0; dy < 3; ++dy) {
        const float* row = base + (y + dy) * stride + xq * 4;
        float4 m = shift3<MX>(ldf4(row), ldf4(row + 4));
        acc = dy ? vop<MX>(acc, m) : m;
    }
    return acc;
}
__device__ __forceinline__ float4 maskq(float4 v, int gx0, int gy, int gz, float NEUT) {
    const bool okzy = ((unsigned)gz < DIMD) & ((unsigned)gy < DIMH);
    float4 r;
    r.x = (okzy & ((unsigned)(gx0 + 0) < DIMW)) ? v.x : NEUT;
    r.y = (okzy & ((unsigned)(gx0 + 1) < DIMW)) ? v.y : NEUT;
    r.z = (okzy & ((unsigned)(gx0 + 2) < DIMW)) ? v.z : NEUT;
    r.w = (okzy & ((unsigned)(gx0 + 3) < DIMW)) ? v.w : NEUT;
    return r;
}
__device__ __forceinline__ float4 relu_sub(float4 a, float4 b) {
    return mk4(fmaxf(a.x-b.x,0.f), fmaxf(a.y-b.y,0.f), fmaxf(a.z-b.z,0.f), fmaxf(a.w-b.w,0.f));
}
__device__ __forceinline__ float4 skup(float4 sk, float4 dl) {
    sk.x += fmaxf(dl.x - sk.x*dl.x, 0.f);
    sk.y += fmaxf(dl.y - sk.y*dl.y, 0.f);
    sk.z += fmaxf(dl.z - sk.z*dl.z, 0.f);
    sk.w += fmaxf(dl.w - sk.w*dl.w, 0.f);
    return sk;
}

// -------- prologue --------
__global__ __launch_bounds__(256) void prologue_kernel(const float* __restrict__ yp,
                                                       const float* __restrict__ yt,
                                                       float* __restrict__ img) {
    int i = blockIdx.x * 256 + threadIdx.x;
    if (i < N4) {
        float4 a = ldf4(yp + i * 4);
        float4 b = ldf4(yt + i * 4);
        float4 s = mk4(sigmoidf_(sigmoidf_(a.x)), sigmoidf_(sigmoidf_(a.y)),
                       sigmoidf_(sigmoidf_(a.z)), sigmoidf_(sigmoidf_(a.w)));
        *(float4*)(img + i * 4) = s;
        *(float4*)(img + N_ELEM + i * 4) = b;
    }
}

// ======== fused 2-iteration kernel, tile 32x8, z-chunk 24, 33 steps ========
// Identical stage/ring structure to the verified ZC=12 version; only z-chunk
// depth and loop bounds changed (ring mod-arithmetic depends on step deltas only).
template<int MODE>
__global__ __launch_bounds__(256) void fused_kernel(const float* __restrict__ V,
                                                    float* __restrict__ eout,
                                                    float* __restrict__ skel) {
    __shared__ alignas(16) float IP[5][14 * 44];   // origin (bx-4, by-3), 40 wide used
    __shared__ alignas(16) float E1A[2][12 * 44];  // origin (bx-3, by-2), +inf masked
    __shared__ alignas(16) float E1B[5][12 * 44];  // origin (bx-3, by-2), -inf masked
    __shared__ alignas(16) float E2A[3][10 * 40];  // origin (bx-2, by-1), -inf masked
    __shared__ alignas(16) float SK[3][8 * 32];    // skel after first delta
    const int tid = threadIdx.x;
    const int vol = blockIdx.z >> 2, zc = blockIdx.z & 3;
    const int bx = blockIdx.x * 32, by = blockIdx.y * 8, bz = zc * 24;
    const float* s = V + (size_t)vol * N_ELEM;

    const int w = tid >> 6, lt = tid & 63;
    const int eo = lt % 5, er = lt / 5;       // E1/E2 task coords (8-wide octet, row)
    const int dq = lt & 7,  dr = lt >> 3;     // D1/D2 task coords (4-wide quad, row)
    const bool isE1 = (w == 0) && (lt < 60);
    const bool isE2 = (w == 1) && (lt < 50);
    const bool isD1 = (w == 2);
    const bool isD2 = (w == 3);

    // loads: IP plane = 14 rows x 40 cols = 560 elems
    int goff[3], loff[3]; bool fok[3];
    #pragma unroll
    for (int k = 0; k < 3; ++k) {
        int f = tid + k * 256;
        fok[k] = f < 560;
        int ly = f / 40, lx = f - ly * 40;
        int gy = min(max(by - 3 + ly, 0), DIMH - 1);
        int gx = min(max(bx - 4 + lx, 0), DIMW - 1);
        goff[k] = fok[k] ? gy * DIMW + gx : 0;
        loff[k] = ly * 44 + lx;
    }

    float4 rA0{}, rA1{}, rB0{}, rB1{}, rC0{}, rC1{};
    float lvA[3], lvB[3];
    float4 skA{}, skB{};

    auto issue = [&](int p, float (&lv)[3]) {
        const int zcl = min(max(bz - 3 + p, 0), DIMD - 1);
        const float* sp = s + (size_t)zcl * DIMH * DIMW;
        #pragma unroll
        for (int k = 0; k < 3; ++k) if (fok[k]) lv[k] = sp[goff[k]];
    };
    auto commit = [&](const float (&lv)[3], float* dp) {
        #pragma unroll
        for (int k = 0; k < 3; ++k) if (fok[k]) dp[loff[k]] = lv[k];
    };
    auto d_gi = [&](int zplane) -> size_t {
        return (size_t)vol * N_ELEM + ((size_t)zplane * DIMH + (by + dr)) * DIMW + bx + dq * 4;
    };
    auto issue_sk = [&](int u, float4& r) {
        if (MODE == 1 && isD1 && u >= 7 && u <= 30) r = ldf4(skel + d_gi(bz + u - 7));
    };

    auto stages = [&](int st, const float4& sk4) {
        if (isE1 && st >= 1 && st <= 30) {
            // xy-min (8-wide) of IP plane bz-4+st
            const float* ip = IP[(st - 1) % 5];
            float4 x0, x1;
            #pragma unroll
            for (int dy = 0; dy < 3; ++dy) {
                const float* row = ip + (er + dy) * 44 + eo * 8;
                float4 A = ldf4(row), B = ldf4(row + 4), C = ldf4(row + 8);
                float4 q0 = shift3<false>(A, B), q1 = shift3<false>(B, C);
                if (dy) { x0 = vop<false>(x0, q0); x1 = vop<false>(x1, q1); }
                else    { x0 = q0; x1 = q1; }
            }
            rA0 = rB0; rA1 = rB1; rB0 = rC0; rB1 = rC1; rC0 = x0; rC1 = x1;
            if (st >= 3) {
                float4 z0 = vop<false>(vop<false>(rA0, rB0), rC0);
                float4 z1 = vop<false>(vop<false>(rA1, rB1), rC1);
                const int gx0 = bx - 3 + eo * 8, gy = by - 2 + er, gz = bz - 5 + st;
                float* a = &E1A[st & 1][er * 44 + eo * 8];
                float* b = &E1B[st % 5][er * 44 + eo * 8];
                *(float4*)(a)     = maskq(z0, gx0,     gy, gz,  INFINITY);
                *(float4*)(a + 4) = maskq(z1, gx0 + 4, gy, gz,  INFINITY);
                *(float4*)(b)     = maskq(z0, gx0,     gy, gz, -INFINITY);
                *(float4*)(b + 4) = maskq(z1, gx0 + 4, gy, gz, -INFINITY);
            }
        }
        if (isE2 && st >= 4 && st <= 31) {
            // xy-min (8-wide) of e1 plane bz-6+st (from +inf-masked copy)
            const float* e1 = E1A[(st - 1) & 1];
            float4 x0, x1;
            #pragma unroll
            for (int dy = 0; dy < 3; ++dy) {
                const float* row = e1 + (er + dy) * 44 + eo * 8;
                float4 A = ldf4(row), B = ldf4(row + 4), C = ldf4(row + 8);
                float4 q0 = shift3<false>(A, B), q1 = shift3<false>(B, C);
                if (dy) { x0 = vop<false>(x0, q0); x1 = vop<false>(x1, q1); }
                else    { x0 = q0; x1 = q1; }
            }
            rA0 = rB0; rA1 = rB1; rB0 = rC0; rB1 = rC1; rC0 = x0; rC1 = x1;
            if (st >= 6) {
                float4 z0 = vop<false>(vop<false>(rA0, rB0), rC0);
                float4 z1 = vop<false>(vop<false>(rA1, rB1), rC1);
                const int gx0 = bx - 2 + eo * 8, gy = by - 1 + er, gz = bz - 7 + st;
                float* d = &E2A[st % 3][er * 40 + eo * 8];
                *(float4*)(d)     = maskq(z0, gx0,     gy, gz, -INFINITY);
                *(float4*)(d + 4) = maskq(z1, gx0 + 4, gy, gz, -INFINITY);
            }
        }
        if (isD1 && st >= 4 && st <= 30) {
            // xy-max (4-wide) of e1 plane bz-6+st; window offset +2 in quad frame
            const float* e1 = E1B[(st - 1) % 5];
            float4 x0;
            #pragma unroll
            for (int dy = 0; dy < 3; ++dy) {
                const float* row = e1 + (dr + 1 + dy) * 44 + dq * 4;
                float4 A = ldf4(row), B = ldf4(row + 4);
                float4 m = shift3c<true>(A, B);
                x0 = dy ? vop<true>(x0, m) : m;
            }
            rA0 = rB0; rB0 = rC0; rC0 = x0;
            if (st >= 7) {
                float4 D = vop<true>(vop<true>(rA0, rB0), rC0);
                // aux = V (=I_{2j}) at output: IP plane bz+st-7, row dr+3, x idx dq*4+4
                const float* ar = &IP[(st - 4) % 5][(dr + 3) * 44 + dq * 4 + 4];
                float4 av = ldf4(ar);
                float4 dl = relu_sub(av, D);
                float4 sk1 = (MODE == 0) ? dl : skup(sk4, dl);
                *(float4*)&SK[st % 3][dr * 32 + dq * 4] = sk1;
            }
        }
        if (isD2 && st >= 7 && st <= 32) {
            // xy-max (4-wide) of e2 plane bz-8+st; window offset +1 in quad frame
            const float* e2 = E2A[(st - 1) % 3];
            float4 x0;
            #pragma unroll
            for (int dy = 0; dy < 3; ++dy) {
                const float* row = e2 + (dr + dy) * 40 + dq * 4;
                float4 A = ldf4(row), B = ldf4(row + 4);
                float4 m = shift3b<true>(A, B);
                x0 = dy ? vop<true>(x0, m) : m;
            }
            rA0 = rB0; rB0 = rC0; rC0 = x0;
            if (st >= 9) {
                float4 D = vop<true>(vop<true>(rA0, rB0), rC0);
                const int zd = bz + st - 9;
                // aux = e1 (=I_{2j+1}) at output: E1B plane zd (written st-4), row dr+2, idx dq*4+3
                const float* ax = &E1B[(st - 4) % 5][(dr + 2) * 44 + dq * 4];
                float4 Aa = ldf4(ax), Ba = ldf4(ax + 4);
                float4 av = mk4(Aa.w, Ba.x, Ba.y, Ba.z);
                // eout = e2 (=I_{2j+2}) at output: E2A plane zd (written st-2), row dr+1, idx dq*4+2
                const float* ex = &E2A[(st - 2) % 3][(dr + 1) * 40 + dq * 4];
                float4 Ae = ldf4(ex), Be = ldf4(ex + 4);
                float4 ev = mk4(Ae.z, Ae.w, Be.x, Be.y);
                float4 sk1 = ldf4(&SK[(st - 2) % 3][dr * 32 + dq * 4]);
                float4 dl = relu_sub(av, D);
                float4 skf = skup(sk1, dl);
                const size_t gi = d_gi(zd);
                *(float4*)(skel + gi) = skf;
                *(float4*)(eout + gi) = ev;
            }
        }
    };

    issue(0, lvA);
    issue(1, lvB);
    issue_sk(7, skB);   // first odd consume; first even consume (u=8) issued in-loop at s=6
    for (int st = 0; st < 33; st += 2) {
        if (st < 30) commit(lvA, IP[st % 5]);
        if (st + 2 < 30) issue(st + 2, lvA);
        stages(st, skA);
        issue_sk(st + 2, skA);
        pipe_barrier();
        const int s1 = st + 1;
        if (s1 < 33) {
            if (s1 < 30) commit(lvB, IP[s1 % 5]);
            if (s1 + 2 < 30) issue(s1 + 2, lvB);
            stages(s1, skB);
            issue_sk(s1 + 2, skB);
            pipe_barrier();
        }
    }
}

// -------- single-iteration tail kernel (delta_16), tile 32x8, z-chunk 24, 30 steps --------
template<int EPI>
__global__ __launch_bounds__(256) void morph_kernel(const float* __restrict__ V,
                                                    float* __restrict__ eout,
                                                    float* __restrict__ skel) {
    __shared__ alignas(16) float IP[5][12 * 40];
    __shared__ alignas(16) float E[4][10 * 36];
    const int tid = threadIdx.x;
    const int vol = blockIdx.z >> 2, zc = blockIdx.z & 3;
    const int bx = blockIdx.x * 32, by = blockIdx.y * 8, bz = zc * 24;
    const float* s = V + (size_t)vol * N_ELEM;

    const int eid = (tid < 90) ? tid : -1;
    const int did = (tid >= 128 && tid < 192) ? tid - 128 : -1;
    const int eq = (eid >= 0) ? eid % 9 : 0, ey = (eid >= 0) ? eid / 9 : 0;
    const int dq = (did >= 0) ? (did & 7) : 0, dyy = (did >= 0) ? (did >> 3) : 0;

    int goff[2], loff[2]; bool fok[2];
    #pragma unroll
    for (int k = 0; k < 2; ++k) {
        int f = tid + k * 256;
        fok[k] = f < 456;
        int ly = f / 38, lx = f - ly * 38;
        int gy = min(max(by - 2 + ly, 0), DIMH - 1);
        int gx = min(max(bx - 2 + lx, 0), DIMW - 1);
        goff[k] = fok[k] ? gy * DIMW + gx : 0;
        loff[k] = ly * 40 + lx;
    }

    float4 r1a{}, r1b{}, r1c{}, r2a{}, r2b{}, r2c{};
    float lvA[2], lvB[2];
    float4 skA{}, skB{};

    auto issue = [&](int p, float (&lv)[2]) {
        const int zcl = min(max(bz - 2 + p, 0), DIMD - 1);
        const float* sp = s + (size_t)zcl * DIMH * DIMW;
        #pragma unroll
        for (int k = 0; k < 2; ++k) lv[k] = sp[goff[k]];
    };
    auto commit = [&](const float (&lv)[2], float* dp) {
        #pragma unroll
        for (int k = 0; k < 2; ++k) if (fok[k]) dp[loff[k]] = lv[k];
    };
    auto sk_gi = [&](int st) -> size_t {
        const int zd = bz - 6 + st;
        return (size_t)vol * N_ELEM + ((size_t)zd * DIMH + (by + dyy)) * DIMW + bx + dq * 4;
    };
    auto issue_sk = [&](int st, float4& r) {
        if (EPI == 2 && did >= 0 && st >= 6 && st <= 29) r = ldf4(skel + sk_gi(st));
    };
    auto stages = [&](int st, const float4& sk4) {
        if (eid >= 0 && st >= 1 && st <= 28) {
            float4 a1 = xy3<false>(IP[(st - 1) % 5], 40, ey, eq);
            r1a = r1b; r1b = r1c; r1c = a1;
            if (st >= 3) {
                float4 e1 = vop<false>(vop<false>(r1a, r1b), r1c);
                e1 = maskq(e1, bx - 1 + eq * 4, by - 1 + ey, bz - 4 + st, -INFINITY);
                *(float4*)&E[st & 3][ey * 36 + eq * 4] = e1;
            }
        }
        if (did >= 0 && st >= 4 && st <= 29) {
            float4 a2 = xy3<true>(E[(st - 1) & 3], 36, dyy, dq);
            r2a = r2b; r2b = r2c; r2c = a2;
            if (st >= 6) {
                float4 D = vop<true>(vop<true>(r2a, r2b), r2c);
                const float* ar = &IP[(st - 4) % 5][(dyy + 2) * 40 + dq * 4];
                float4 P = ldf4(ar), Q = ldf4(ar + 4);
                float4 av = mk4(P.z, P.w, Q.x, Q.y);
                const float* er = &E[(st - 2) & 3][(dyy + 1) * 36 + dq * 4];
                float4 R = ldf4(er), S = ldf4(er + 4);
                float4 ev = mk4(R.y, R.z, R.w, S.x);
                const size_t gi = sk_gi(st);
                float4 dl = relu_sub(av, D);
                if (EPI == 1) {
                    *(float4*)(skel + gi) = dl;
                } else {
                    *(float4*)(skel + gi) = skup(sk4, dl);
                }
                *(float4*)(eout + gi) = ev;
            }
        }
    };

    issue(0, lvA);
    issue(1, lvB);
    issue_sk(6, skA);
    issue_sk(7, skB);
    for (int st = 0; st < 30; st += 2) {
        if (st < 28) commit(lvA, IP[st % 5]);
        if (st + 2 < 28) issue(st + 2, lvA);
        stages(st, skA);
        issue_sk(st + 2, skA);
        pipe_barrier();
        const int s1 = st + 1;
        if (s1 < 28) commit(lvB, IP[s1 % 5]);
        if (s1 + 2 < 28) issue(s1 + 2, lvB);
        stages(s1, skB);
        issue_sk(s1 + 2, skB);
        pipe_barrier();
    }
}

// -------- reductions --------
__device__ __forceinline__ double wave_block_reduce(double v, double* red4) {
    for (int off = 32; off > 0; off >>= 1) v += __shfl_down(v, off, 64);
    int wid = threadIdx.x >> 6, lane = threadIdx.x & 63;
    if (lane == 0) red4[wid] = v;
    __syncthreads();
    double r = red4[0] + red4[1] + red4[2] + red4[3];
    __syncthreads();
    return r;
}

__global__ __launch_bounds__(256) void reduce_partial(const float* __restrict__ yp,
                                                      const float* __restrict__ yt,
                                                      const float* __restrict__ sp,
                                                      const float* __restrict__ st,
                                                      double* __restrict__ partials) {
    double acc[10];
    #pragma unroll
    for (int k = 0; k < 10; ++k) acc[k] = 0.0;

    for (int i = blockIdx.x * 256 + threadIdx.x; i < N4; i += RBLOCKS * 256) {
        float4 x = ldf4(yp + i * 4);
        float4 t = ldf4(yt + i * 4);
        float4 a = ldf4(sp + i * 4);
        float4 b = ldf4(st + i * 4);
        #pragma unroll
        for (int c = 0; c < 4; ++c) {
            float xc = (&x.x)[c], tc = (&t.x)[c], ac = (&a.x)[c], bc = (&b.x)[c];
            float s1 = sigmoidf_(xc);
            float s2 = sigmoidf_(s1);
            float w  = expf(-0.5f * bc * bc);
            acc[0] += (double)(ac * tc);
            acc[1] += (double)ac;
            acc[2] += (double)(bc * s2);
            acc[3] += (double)bc;
            acc[4] += (double)(w * s1 * tc);
            acc[5] += (double)(w * s1);
            acc[6] += (double)(w * tc);
            acc[7] += (double)(s1 * tc);
            acc[8] += (double)s1;
            acc[9] += (double)tc;
        }
    }

    __shared__ double red4[4];
    #pragma unroll
    for (int k = 0; k < 10; ++k) {
        double r = wave_block_reduce(acc[k], red4);
        if (threadIdx.x == 0) partials[blockIdx.x * 10 + k] = r;
        __syncthreads();
    }
}

__global__ __launch_bounds__(256) void finalize_kernel(const double* __restrict__ partials,
                                                       float* __restrict__ out) {
    __shared__ double sums[10];
    __shared__ double red4[4];
    for (int k = 0; k < 10; ++k) {
        double v = 0.0;
        for (int j = threadIdx.x; j < RBLOCKS; j += 256) v += partials[j * 10 + k];
        double r = wave_block_reduce(v, red4);
        if (threadIdx.x == 0) sums[k] = r;
        __syncthreads();
    }
    if (threadIdx.x == 0) {
        double tprec = (sums[0] + 1.0) / (sums[1] + 1.0);
        double tsens = (sums[2] + 1.0) / (sums[3] + 1.0);
        double cldice = 1.0 - 2.0 * (tprec * tsens) / (tprec + tsens + 1.0);
        double boundary = 1.0 - (2.0 * sums[4] + 1.0) / (sums[5] + sums[6] + 1.0);
        double dice = 1.0 - (2.0 * sums[7] + 1.0) / (sums[8] + sums[9] + 1.0);
        out[0] = (float)(0.5 * cldice + 0.3 * boundary + 0.2 * dice);
    }
}

extern "C" void kernel_launch(void* const* d_in, const int* in_sizes, int n_in,
                              void* d_out, int out_size, void* d_ws, size_t ws_size,
                              hipStream_t stream) {
    const float* y_pred = (const float*)d_in[0];
    const float* y_true = (const float*)d_in[1];
    float* out = (float*)d_out;

    const size_t NB = (size_t)2 * N_ELEM;
    float* imgA = (float*)d_ws;      // I_{2j} ping-pong
    float* imgB = imgA + NB;
    float* skel = imgB + NB;
    double* partials = (double*)(skel + NB);

    dim3 g(DIMW / 32, DIMH / 8, 4 * 2);   // (4, 16, 8); z = vol*4 + zchunk(24 deep)
    dim3 b(256);

    prologue_kernel<<<(N4 + 255) / 256, 256, 0, stream>>>(y_pred, y_true, imgA);

    // delta_0, delta_1; eout = I_2
    fused_kernel<0><<<g, b, 0, stream>>>(imgA, imgB, skel);
    float* cur = imgB;   // I_{2j}
    float* nxt = imgA;
    for (int j = 1; j < 8; ++j) {
        // delta_{2j}, delta_{2j+1}; eout = I_{2j+2}
        fused_kernel<1><<<g, b, 0, stream>>>(cur, nxt, skel);
        float* tmp = cur; cur = nxt; nxt = tmp;
    }
    // cur = I_16: final delta_16
    morph_kernel<2><<<g, b, 0, stream>>>(cur, nxt, skel);

    reduce_partial<<<RBLOCKS, 256, 0, stream>>>(y_pred, y_true, skel, skel + N_ELEM, partials);
    finalize_kernel<<<1, 256, 0, stream>>>(partials, out);
}

// Round 15
// 232.048 us; speedup vs baseline: 1.1906x; 1.1906x over previous
//
#include <hip/hip_runtime.h>
#include <math.h>

// Volume geometry (1,1,96,128,128)
#define DIMD 96
#define DIMH 128
#define DIMW 128
#define N_ELEM (DIMD*DIMH*DIMW)   // 1,572,864
#define N4 (N_ELEM/4)

#define RBLOCKS 512

__device__ __forceinline__ float sigmoidf_(float x) { return 1.0f / (1.0f + expf(-x)); }
__device__ __forceinline__ float4 mk4(float a, float b, float c, float d) {
    float4 r; r.x = a; r.y = b; r.z = c; r.w = d; return r;
}
__device__ __forceinline__ float4 ldf4(const float* p) { return *(const float4*)p; }

// Barrier WITHOUT vmcnt drain: LDS producer->consumer fence only.
__device__ __forceinline__ void pipe_barrier() {
    asm volatile("s_waitcnt lgkmcnt(0)" ::: "memory");
    __builtin_amdgcn_s_barrier();
    asm volatile("" ::: "memory");
}

// lane l <- lane l+1 (wave_shr:1). Invalid lanes get 0 (bound_ctrl old=0);
// only garbage-tolerated boundary octets consume those.
__device__ __forceinline__ float dpp_wfshr1(float x) {
    int r = __builtin_amdgcn_update_dpp(0, __builtin_bit_cast(int, x),
                                        0x138, 0xF, 0xF, false);
    return __builtin_bit_cast(float, r);
}

template<bool MX> __device__ __forceinline__ float op2(float a, float b) {
    return MX ? fmaxf(a, b) : fminf(a, b);
}
template<bool MX> __device__ __forceinline__ float op3(float a, float b, float c) {
    return op2<MX>(op2<MX>(a, b), c);   // -> v_min3/v_max3
}
template<bool MX> __device__ __forceinline__ float4 vop(float4 a, float4 b) {
    return mk4(op2<MX>(a.x,b.x), op2<MX>(a.y,b.y), op2<MX>(a.z,b.z), op2<MX>(a.w,b.w));
}
// window starts at +0 / +1 / +2 within concat(A,B)
template<bool MX> __device__ __forceinline__ float4 shift3(float4 A, float4 B) {
    return mk4(op3<MX>(A.x,A.y,A.z), op3<MX>(A.y,A.z,A.w),
               op3<MX>(A.z,A.w,B.x), op3<MX>(A.w,B.x,B.y));
}
template<bool MX> __device__ __forceinline__ float4 shift3b(float4 A, float4 B) {
    return mk4(op3<MX>(A.y,A.z,A.w), op3<MX>(A.z,A.w,B.x),
               op3<MX>(A.w,B.x,B.y), op3<MX>(B.x,B.y,B.z));
}
template<bool MX> __device__ __forceinline__ float4 shift3c(float4 A, float4 B) {
    return mk4(op3<MX>(A.z,A.w,B.x), op3<MX>(A.w,B.x,B.y),
               op3<MX>(B.x,B.y,B.z), op3<MX>(B.y,B.z,B.w));
}
template<bool MX> __device__ __forceinline__ float4 xy3(const float* base, int stride, int y, int xq) {
    float4 acc;
    #pragma unroll
    for (int dy = 0; dy < 3; ++dy) {
        const float* row = base + (y + dy) * stride + xq * 4;
        float4 m = shift3<MX>(ldf4(row), ldf4(row + 4));
        acc = dy ? vop<MX>(acc, m) : m;
    }
    return acc;
}
__device__ __forceinline__ float4 maskq(float4 v, int gx0, int gy, int gz, float NEUT) {
    const bool okzy = ((unsigned)gz < DIMD) & ((unsigned)gy < DIMH);
    float4 r;
    r.x = (okzy & ((unsigned)(gx0 + 0) < DIMW)) ? v.x : NEUT;
    r.y = (okzy & ((unsigned)(gx0 + 1) < DIMW)) ? v.y : NEUT;
    r.z = (okzy & ((unsigned)(gx0 + 2) < DIMW)) ? v.z : NEUT;
    r.w = (okzy & ((unsigned)(gx0 + 3) < DIMW)) ? v.w : NEUT;
    return r;
}
__device__ __forceinline__ float4 relu_sub(float4 a, float4 b) {
    return mk4(fmaxf(a.x-b.x,0.f), fmaxf(a.y-b.y,0.f), fmaxf(a.z-b.z,0.f), fmaxf(a.w-b.w,0.f));
}
__device__ __forceinline__ float4 skup(float4 sk, float4 dl) {
    sk.x += fmaxf(dl.x - sk.x*dl.x, 0.f);
    sk.y += fmaxf(dl.y - sk.y*dl.y, 0.f);
    sk.z += fmaxf(dl.z - sk.z*dl.z, 0.f);
    sk.w += fmaxf(dl.w - sk.w*dl.w, 0.f);
    return sk;
}

// -------- prologue --------
__global__ __launch_bounds__(256) void prologue_kernel(const float* __restrict__ yp,
                                                       const float* __restrict__ yt,
                                                       float* __restrict__ img) {
    int i = blockIdx.x * 256 + threadIdx.x;
    if (i < N4) {
        float4 a = ldf4(yp + i * 4);
        float4 b = ldf4(yt + i * 4);
        float4 s = mk4(sigmoidf_(sigmoidf_(a.x)), sigmoidf_(sigmoidf_(a.y)),
                       sigmoidf_(sigmoidf_(a.z)), sigmoidf_(sigmoidf_(a.w)));
        *(float4*)(img + i * 4) = s;
        *(float4*)(img + N_ELEM + i * 4) = b;
    }
}

// ======== fused 2-iteration kernel, tile 32x8, z-chunk 12, 21 steps ========
// = verified Round-10 kernel + (a) f4 loader/commit, (b) E1/E2 third stencil
// read replaced by DPP wave_shr:1 of the neighbor lane's A (C.x,C.y only).
template<int MODE>
__global__ __launch_bounds__(256) void fused_kernel(const float* __restrict__ V,
                                                    float* __restrict__ eout,
                                                    float* __restrict__ skel) {
    __shared__ alignas(16) float IP[5][14 * 44];   // origin (bx-4, by-3), 40 wide used
    __shared__ alignas(16) float E1A[2][12 * 44];  // origin (bx-3, by-2), +inf masked
    __shared__ alignas(16) float E1B[5][12 * 44];  // origin (bx-3, by-2), -inf masked
    __shared__ alignas(16) float E2A[3][10 * 40];  // origin (bx-2, by-1), -inf masked
    __shared__ alignas(16) float SK[3][8 * 32];    // skel after first delta
    const int tid = threadIdx.x;
    const int vol = blockIdx.z >> 3, zc = blockIdx.z & 7;
    const int bx = blockIdx.x * 32, by = blockIdx.y * 8, bz = zc * 12;
    const float* s = V + (size_t)vol * N_ELEM;

    const int w = tid >> 6, lt = tid & 63;
    const int eo = lt % 5, er = lt / 5;       // E1/E2 task coords (8-wide octet, row)
    const int dq = lt & 7,  dr = lt >> 3;     // D1/D2 task coords (4-wide quad, row)
    const bool isE1 = (w == 0) && (lt < 60);
    const bool isE2 = (w == 1) && (lt < 50);
    const bool isD1 = (w == 2);
    const bool isD2 = (w == 3);

    // loader: 14 rows x 10 f4-cols = 140 float4 tasks
    const bool isLd = (tid < 140);
    const int  lly  = tid / 10, llx = (tid % 10) * 4;
    const int  gyo  = min(max(by - 3 + lly, 0), DIMH - 1);
    const int  loff = lly * 44 + llx;
    const bool xint = (bx != 0) && (bx != DIMW - 32);
    const int gxc0 = min(max(bx - 4 + llx + 0, 0), DIMW - 1);
    const int gxc1 = min(max(bx - 4 + llx + 1, 0), DIMW - 1);
    const int gxc2 = min(max(bx - 4 + llx + 2, 0), DIMW - 1);
    const int gxc3 = min(max(bx - 4 + llx + 3, 0), DIMW - 1);

    float4 rA0{}, rA1{}, rB0{}, rB1{}, rC0{}, rC1{};
    float4 lvA{}, lvB{};
    float4 skA{}, skB{};

    auto issue = [&](int p, float4& lv) {
        if (!isLd) return;
        const int zcl = min(max(bz - 3 + p, 0), DIMD - 1);
        const float* sp = s + (size_t)zcl * DIMH * DIMW + (size_t)gyo * DIMW;
        if (xint) lv = ldf4(sp + (bx - 4 + llx));
        else      lv = mk4(sp[gxc0], sp[gxc1], sp[gxc2], sp[gxc3]);
    };
    auto commit = [&](const float4& lv, float* dp) {
        if (isLd) *(float4*)(dp + loff) = lv;
    };
    auto d_gi = [&](int zplane) -> size_t {
        return (size_t)vol * N_ELEM + ((size_t)zplane * DIMH + (by + dr)) * DIMW + bx + dq * 4;
    };
    auto issue_sk = [&](int u, float4& r) {
        if (MODE == 1 && isD1 && u >= 7 && u <= 18) r = ldf4(skel + d_gi(bz + u - 7));
    };

    auto stages = [&](int st, const float4& sk4) {
        if (isE1 && st >= 1 && st <= 18) {
            // xy-min (8-wide) of IP plane bz-4+st; C.x,C.y via DPP from lane+1's A
            const float* ip = IP[(st - 1) % 5];
            float4 x0, x1;
            #pragma unroll
            for (int dy = 0; dy < 3; ++dy) {
                const float* row = ip + (er + dy) * 44 + eo * 8;
                float4 A = ldf4(row), B = ldf4(row + 4);
                float4 C = mk4(dpp_wfshr1(A.x), dpp_wfshr1(A.y), 0.f, 0.f);
                float4 q0 = shift3<false>(A, B), q1 = shift3<false>(B, C);
                if (dy) { x0 = vop<false>(x0, q0); x1 = vop<false>(x1, q1); }
                else    { x0 = q0; x1 = q1; }
            }
            rA0 = rB0; rA1 = rB1; rB0 = rC0; rB1 = rC1; rC0 = x0; rC1 = x1;
            if (st >= 3) {
                float4 z0 = vop<false>(vop<false>(rA0, rB0), rC0);
                float4 z1 = vop<false>(vop<false>(rA1, rB1), rC1);
                const int gx0 = bx - 3 + eo * 8, gy = by - 2 + er, gz = bz - 5 + st;
                float* a = &E1A[st & 1][er * 44 + eo * 8];
                float* b = &E1B[st % 5][er * 44 + eo * 8];
                *(float4*)(a)     = maskq(z0, gx0,     gy, gz,  INFINITY);
                *(float4*)(a + 4) = maskq(z1, gx0 + 4, gy, gz,  INFINITY);
                *(float4*)(b)     = maskq(z0, gx0,     gy, gz, -INFINITY);
                *(float4*)(b + 4) = maskq(z1, gx0 + 4, gy, gz, -INFINITY);
            }
        }
        if (isE2 && st >= 4 && st <= 19) {
            // xy-min (8-wide) of e1 plane bz-6+st (+inf-masked copy); C via DPP
            const float* e1 = E1A[(st - 1) & 1];
            float4 x0, x1;
            #pragma unroll
            for (int dy = 0; dy < 3; ++dy) {
                const float* row = e1 + (er + dy) * 44 + eo * 8;
                float4 A = ldf4(row), B = ldf4(row + 4);
                float4 C = mk4(dpp_wfshr1(A.x), dpp_wfshr1(A.y), 0.f, 0.f);
                float4 q0 = shift3<false>(A, B), q1 = shift3<false>(B, C);
                if (dy) { x0 = vop<false>(x0, q0); x1 = vop<false>(x1, q1); }
                else    { x0 = q0; x1 = q1; }
            }
            rA0 = rB0; rA1 = rB1; rB0 = rC0; rB1 = rC1; rC0 = x0; rC1 = x1;
            if (st >= 6) {
                float4 z0 = vop<false>(vop<false>(rA0, rB0), rC0);
                float4 z1 = vop<false>(vop<false>(rA1, rB1), rC1);
                const int gx0 = bx - 2 + eo * 8, gy = by - 1 + er, gz = bz - 7 + st;
                float* d = &E2A[st % 3][er * 40 + eo * 8];
                *(float4*)(d)     = maskq(z0, gx0,     gy, gz, -INFINITY);
                *(float4*)(d + 4) = maskq(z1, gx0 + 4, gy, gz, -INFINITY);
            }
        }
        if (isD1 && st >= 4 && st <= 18) {
            // xy-max (4-wide) of e1 plane bz-6+st; window offset +2 in quad frame
            const float* e1 = E1B[(st - 1) % 5];
            float4 x0;
            #pragma unroll
            for (int dy = 0; dy < 3; ++dy) {
                const float* row = e1 + (dr + 1 + dy) * 44 + dq * 4;
                float4 A = ldf4(row), B = ldf4(row + 4);
                float4 m = shift3c<true>(A, B);
                x0 = dy ? vop<true>(x0, m) : m;
            }
            rA0 = rB0; rB0 = rC0; rC0 = x0;
            if (st >= 7) {
                float4 D = vop<true>(vop<true>(rA0, rB0), rC0);
                // aux = V (=I_{2j}) at output: IP plane bz+st-7, row dr+3, x idx dq*4+4
                const float* ar = &IP[(st - 4) % 5][(dr + 3) * 44 + dq * 4 + 4];
                float4 av = ldf4(ar);
                float4 dl = relu_sub(av, D);
                float4 sk1 = (MODE == 0) ? dl : skup(sk4, dl);
                *(float4*)&SK[st % 3][dr * 32 + dq * 4] = sk1;
            }
        }
        if (isD2 && st >= 7 && st <= 20) {
            // xy-max (4-wide) of e2 plane bz-8+st; window offset +1 in quad frame
            const float* e2 = E2A[(st - 1) % 3];
            float4 x0;
            #pragma unroll
            for (int dy = 0; dy < 3; ++dy) {
                const float* row = e2 + (dr + dy) * 40 + dq * 4;
                float4 A = ldf4(row), B = ldf4(row + 4);
                float4 m = shift3b<true>(A, B);
                x0 = dy ? vop<true>(x0, m) : m;
            }
            rA0 = rB0; rB0 = rC0; rC0 = x0;
            if (st >= 9) {
                float4 D = vop<true>(vop<true>(rA0, rB0), rC0);
                const int zd = bz + st - 9;
                // aux = e1 (=I_{2j+1}) at output: E1B plane zd (written st-4), row dr+2, idx dq*4+3
                const float* ax = &E1B[(st - 4) % 5][(dr + 2) * 44 + dq * 4];
                float4 Aa = ldf4(ax), Ba = ldf4(ax + 4);
                float4 av = mk4(Aa.w, Ba.x, Ba.y, Ba.z);
                // eout = e2 (=I_{2j+2}) at output: E2A plane zd (written st-2), row dr+1, idx dq*4+2
                const float* ex = &E2A[(st - 2) % 3][(dr + 1) * 40 + dq * 4];
                float4 Ae = ldf4(ex), Be = ldf4(ex + 4);
                float4 ev = mk4(Ae.z, Ae.w, Be.x, Be.y);
                float4 sk1 = ldf4(&SK[(st - 2) % 3][dr * 32 + dq * 4]);
                float4 dl = relu_sub(av, D);
                float4 skf = skup(sk1, dl);
                const size_t gi = d_gi(zd);
                *(float4*)(skel + gi) = skf;
                *(float4*)(eout + gi) = ev;
            }
        }
    };

    issue(0, lvA);
    issue(1, lvB);
    issue_sk(7, skB);   // first odd consume; first even consume (u=8) issued in-loop at s=6
    for (int st = 0; st < 21; st += 2) {
        if (st < 18) commit(lvA, IP[st % 5]);
        if (st + 2 < 18) issue(st + 2, lvA);
        stages(st, skA);
        issue_sk(st + 2, skA);
        pipe_barrier();
        const int s1 = st + 1;
        if (s1 < 21) {
            if (s1 < 18) commit(lvB, IP[s1 % 5]);
            if (s1 + 2 < 18) issue(s1 + 2, lvB);
            stages(s1, skB);
            issue_sk(s1 + 2, skB);
            pipe_barrier();
        }
    }
}

// -------- single-iteration tail kernel (delta_16), verified Round-8/10 structure --------
template<int EPI>
__global__ __launch_bounds__(256) void morph_kernel(const float* __restrict__ V,
                                                    float* __restrict__ eout,
                                                    float* __restrict__ skel) {
    __shared__ alignas(16) float IP[5][12 * 40];
    __shared__ alignas(16) float E[4][10 * 36];
    const int tid = threadIdx.x;
    const int vol = blockIdx.z >> 3, zc = blockIdx.z & 7;
    const int bx = blockIdx.x * 32, by = blockIdx.y * 8, bz = zc * 12;
    const float* s = V + (size_t)vol * N_ELEM;

    const int eid = (tid < 90) ? tid : -1;
    const int did = (tid >= 128 && tid < 192) ? tid - 128 : -1;
    const int eq = (eid >= 0) ? eid % 9 : 0, ey = (eid >= 0) ? eid / 9 : 0;
    const int dq = (did >= 0) ? (did & 7) : 0, dyy = (did >= 0) ? (did >> 3) : 0;

    int goff[2], loff[2]; bool fok[2];
    #pragma unroll
    for (int k = 0; k < 2; ++k) {
        int f = tid + k * 256;
        fok[k] = f < 456;
        int ly = f / 38, lx = f - ly * 38;
        int gy = min(max(by - 2 + ly, 0), DIMH - 1);
        int gx = min(max(bx - 2 + lx, 0), DIMW - 1);
        goff[k] = fok[k] ? gy * DIMW + gx : 0;
        loff[k] = ly * 40 + lx;
    }

    float4 r1a{}, r1b{}, r1c{}, r2a{}, r2b{}, r2c{};
    float lvA[2], lvB[2];
    float4 skA{}, skB{};

    auto issue = [&](int p, float (&lv)[2]) {
        const int zcl = min(max(bz - 2 + p, 0), DIMD - 1);
        const float* sp = s + (size_t)zcl * DIMH * DIMW;
        #pragma unroll
        for (int k = 0; k < 2; ++k) lv[k] = sp[goff[k]];
    };
    auto commit = [&](const float (&lv)[2], float* dp) {
        #pragma unroll
        for (int k = 0; k < 2; ++k) if (fok[k]) dp[loff[k]] = lv[k];
    };
    auto sk_gi = [&](int st) -> size_t {
        const int zd = bz - 6 + st;
        return (size_t)vol * N_ELEM + ((size_t)zd * DIMH + (by + dyy)) * DIMW + bx + dq * 4;
    };
    auto issue_sk = [&](int st, float4& r) {
        if (EPI == 2 && did >= 0 && st >= 6 && st <= 17) r = ldf4(skel + sk_gi(st));
    };
    auto stages = [&](int st, const float4& sk4) {
        if (eid >= 0 && st >= 1 && st <= 16) {
            float4 a1 = xy3<false>(IP[(st - 1) % 5], 40, ey, eq);
            r1a = r1b; r1b = r1c; r1c = a1;
            if (st >= 3) {
                float4 e1 = vop<false>(vop<false>(r1a, r1b), r1c);
                e1 = maskq(e1, bx - 1 + eq * 4, by - 1 + ey, bz - 4 + st, -INFINITY);
                *(float4*)&E[st & 3][ey * 36 + eq * 4] = e1;
            }
        }
        if (did >= 0 && st >= 4 && st <= 17) {
            float4 a2 = xy3<true>(E[(st - 1) & 3], 36, dyy, dq);
            r2a = r2b; r2b = r2c; r2c = a2;
            if (st >= 6) {
                float4 D = vop<true>(vop<true>(r2a, r2b), r2c);
                const float* ar = &IP[(st - 4) % 5][(dyy + 2) * 40 + dq * 4];
                float4 P = ldf4(ar), Q = ldf4(ar + 4);
                float4 av = mk4(P.z, P.w, Q.x, Q.y);
                const float* er = &E[(st - 2) & 3][(dyy + 1) * 36 + dq * 4];
                float4 R = ldf4(er), S = ldf4(er + 4);
                float4 ev = mk4(R.y, R.z, R.w, S.x);
                const size_t gi = sk_gi(st);
                float4 dl = relu_sub(av, D);
                if (EPI == 1) {
                    *(float4*)(skel + gi) = dl;
                } else {
                    *(float4*)(skel + gi) = skup(sk4, dl);
                }
                *(float4*)(eout + gi) = ev;
            }
        }
    };

    issue(0, lvA);
    issue(1, lvB);
    issue_sk(6, skA);
    issue_sk(7, skB);
    for (int st = 0; st < 18; st += 2) {
        if (st < 16) commit(lvA, IP[st % 5]);
        if (st + 2 < 16) issue(st + 2, lvA);
        stages(st, skA);
        issue_sk(st + 2, skA);
        pipe_barrier();
        const int s1 = st + 1;
        if (s1 < 16) commit(lvB, IP[s1 % 5]);
        if (s1 + 2 < 16) issue(s1 + 2, lvB);
        stages(s1, skB);
        issue_sk(s1 + 2, skB);
        pipe_barrier();
    }
}

// -------- reductions --------
__device__ __forceinline__ double wave_block_reduce(double v, double* red4) {
    for (int off = 32; off > 0; off >>= 1) v += __shfl_down(v, off, 64);
    int wid = threadIdx.x >> 6, lane = threadIdx.x & 63;
    if (lane == 0) red4[wid] = v;
    __syncthreads();
    double r = red4[0] + red4[1] + red4[2] + red4[3];
    __syncthreads();
    return r;
}

__global__ __launch_bounds__(256) void reduce_partial(const float* __restrict__ yp,
                                                      const float* __restrict__ yt,
                                                      const float* __restrict__ sp,
                                                      const float* __restrict__ st,
                                                      double* __restrict__ partials) {
    double acc[10];
    #pragma unroll
    for (int k = 0; k < 10; ++k) acc[k] = 0.0;

    for (int i = blockIdx.x * 256 + threadIdx.x; i < N4; i += RBLOCKS * 256) {
        float4 x = ldf4(yp + i * 4);
        float4 t = ldf4(yt + i * 4);
        float4 a = ldf4(sp + i * 4);
        float4 b = ldf4(st + i * 4);
        #pragma unroll
        for (int c = 0; c < 4; ++c) {
            float xc = (&x.x)[c], tc = (&t.x)[c], ac = (&a.x)[c], bc = (&b.x)[c];
            float s1 = sigmoidf_(xc);
            float s2 = sigmoidf_(s1);
            float w  = expf(-0.5f * bc * bc);
            acc[0] += (double)(ac * tc);
            acc[1] += (double)ac;
            acc[2] += (double)(bc * s2);
            acc[3] += (double)bc;
            acc[4] += (double)(w * s1 * tc);
            acc[5] += (double)(w * s1);
            acc[6] += (double)(w * tc);
            acc[7] += (double)(s1 * tc);
            acc[8] += (double)s1;
            acc[9] += (double)tc;
        }
    }

    __shared__ double red4[4];
    #pragma unroll
    for (int k = 0; k < 10; ++k) {
        double r = wave_block_reduce(acc[k], red4);
        if (threadIdx.x == 0) partials[blockIdx.x * 10 + k] = r;
        __syncthreads();
    }
}

__global__ __launch_bounds__(256) void finalize_kernel(const double* __restrict__ partials,
                                                       float* __restrict__ out) {
    __shared__ double sums[10];
    __shared__ double red4[4];
    for (int k = 0; k < 10; ++k) {
        double v = 0.0;
        for (int j = threadIdx.x; j < RBLOCKS; j += 256) v += partials[j * 10 + k];
        double r = wave_block_reduce(v, red4);
        if (threadIdx.x == 0) sums[k] = r;
        __syncthreads();
    }
    if (threadIdx.x == 0) {
        double tprec = (sums[0] + 1.0) / (sums[1] + 1.0);
        double tsens = (sums[2] + 1.0) / (sums[3] + 1.0);
        double cldice = 1.0 - 2.0 * (tprec * tsens) / (tprec + tsens + 1.0);
        double boundary = 1.0 - (2.0 * sums[4] + 1.0) / (sums[5] + sums[6] + 1.0);
        double dice = 1.0 - (2.0 * sums[7] + 1.0) / (sums[8] + sums[9] + 1.0);
        out[0] = (float)(0.5 * cldice + 0.3 * boundary + 0.2 * dice);
    }
}

extern "C" void kernel_launch(void* const* d_in, const int* in_sizes, int n_in,
                              void* d_out, int out_size, void* d_ws, size_t ws_size,
                              hipStream_t stream) {
    const float* y_pred = (const float*)d_in[0];
    const float* y_true = (const float*)d_in[1];
    float* out = (float*)d_out;

    const size_t NB = (size_t)2 * N_ELEM;
    float* imgA = (float*)d_ws;      // I_{2j} ping-pong
    float* imgB = imgA + NB;
    float* skel = imgB + NB;
    double* partials = (double*)(skel + NB);

    dim3 g(DIMW / 32, DIMH / 8, 8 * 2);   // (4, 16, 16); z = vol*8 + zchunk(12 deep)
    dim3 b(256);

    prologue_kernel<<<(N4 + 255) / 256, 256, 0, stream>>>(y_pred, y_true, imgA);

    // delta_0, delta_1; eout = I_2
    fused_kernel<0><<<g, b, 0, stream>>>(imgA, imgB, skel);
    float* cur = imgB;   // I_{2j}
    float* nxt = imgA;
    for (int j = 1; j < 8; ++j) {
        // delta_{2j}, delta_{2j+1}; eout = I_{2j+2}
        fused_kernel<1><<<g, b, 0, stream>>>(cur, nxt, skel);
        float* tmp = cur; cur = nxt; nxt = tmp;
    }
    // cur = I_16: final delta_16
    morph_kernel<2><<<g, b, 0, stream>>>(cur, nxt, skel);

    reduce_partial<<<RBLOCKS, 256, 0, stream>>>(y_pred, y_true, skel, skel + N_ELEM, partials);
    finalize_kernel<<<1, 256, 0, stream>>>(partials, out);
}